// Round 6
// baseline (405.594 us; speedup 1.0000x reference)
//
#include <hip/hip_runtime.h>
#include <math.h>

#define B_ 4
#define S_ 2048
#define DM_ 1024
#define DK_ 128

static constexpr float SCALE = 0.08838834764831845f; // 1/sqrt(128)

__device__ __forceinline__ unsigned enc_f32(float f){
  unsigned u = __float_as_uint(f);
  return (u & 0x80000000u) ? ~u : (u | 0x80000000u);
}
__device__ __forceinline__ float dec_f32(unsigned u){
  unsigned v = (u & 0x80000000u) ? (u & 0x7FFFFFFFu) : ~u;
  return __uint_as_float(v);
}
__device__ __forceinline__ float f4get(const float4& v, int i){
  switch(i){ case 0: return v.x; case 1: return v.y; case 2: return v.z; default: return v.w; }
}

// ---- init: column-max to enc(-inf) ----
__global__ __launch_bounds__(256) void init_kernel(unsigned* __restrict__ cmax){
  int i = blockIdx.x*256 + threadIdx.x;
  if(i < B_*S_) cmax[i] = 0x007FFFFFu; // enc(-INF)
}

// ---- QKV GEMM (32-row tiles, no reg prefetch: proven non-spilling form) ----
__global__ __launch_bounds__(256) void qkv_kernel(
    const float* __restrict__ X, const float* __restrict__ Wq,
    const float* __restrict__ Wk, const float* __restrict__ Wv,
    float* __restrict__ Q, float* __restrict__ Kt, float* __restrict__ V)
{
  __shared__ __align__(16) float smem[32*68 + 64*128];  // Xs[32][68] + Ws[64][128]
  float* Xs = smem;
  float* Ws = smem + 32*68;
  const int tid = threadIdx.x;
  const int which = blockIdx.y;
  const float* Wm = (which==0) ? Wq : ((which==1) ? Wk : Wv);
  const int m0 = blockIdx.x * 32;
  const int tx = tid & 31, ty = tid >> 5;     // cols tx*4.., rows ty*4..
  float acc[4][4] = {};
  for(int k0 = 0; k0 < DM_; k0 += 64){
    __syncthreads();
    #pragma unroll
    for(int l=0;l<2;l++){                     // X tile 32x64
      int p = tid + 256*l;
      int r = p >> 4, c = (p & 15) << 2;
      *reinterpret_cast<float4*>(&Xs[r*68 + c]) =
        *reinterpret_cast<const float4*>(&X[(size_t)(m0+r)*DM_ + k0 + c]);
    }
    #pragma unroll
    for(int l=0;l<8;l++){                     // W tile 64x128 (k-major)
      int p = tid + 256*l;
      int r = p >> 5, c = (p & 31) << 2;
      *reinterpret_cast<float4*>(&Ws[r*128 + c]) =
        *reinterpret_cast<const float4*>(&Wm[(size_t)(k0+r)*DK_ + c]);
    }
    __syncthreads();
    #pragma unroll 4
    for(int kk=0;kk<64;kk+=4){
      float4 xr[4];
      #pragma unroll
      for(int i=0;i<4;i++) xr[i] = *reinterpret_cast<const float4*>(&Xs[(ty*4+i)*68 + kk]);
      #pragma unroll
      for(int k2=0;k2<4;k2++){
        float4 wv = *reinterpret_cast<const float4*>(&Ws[(kk+k2)*128 + tx*4]);
        #pragma unroll
        for(int i=0;i<4;i++){
          float xv = f4get(xr[i], k2);
          acc[i][0] = fmaf(xv, wv.x, acc[i][0]);
          acc[i][1] = fmaf(xv, wv.y, acc[i][1]);
          acc[i][2] = fmaf(xv, wv.z, acc[i][2]);
          acc[i][3] = fmaf(xv, wv.w, acc[i][3]);
        }
      }
    }
  }
  const int b = m0 >> 11;
  if(which != 1){
    float* O = (which==0) ? Q : V;
    #pragma unroll
    for(int i=0;i<4;i++){
      float4 v = {acc[i][0],acc[i][1],acc[i][2],acc[i][3]};
      *reinterpret_cast<float4*>(&O[(size_t)(m0 + ty*4 + i)*DK_ + tx*4]) = v;
    }
  } else {
    __syncthreads();
    float* Tmp = smem;                        // [32][133]
    #pragma unroll
    for(int i=0;i<4;i++)
      #pragma unroll
      for(int j=0;j<4;j++) Tmp[(ty*4+i)*133 + tx*4 + j] = acc[i][j];
    __syncthreads();
    const int s0 = m0 & (S_-1);
    #pragma unroll
    for(int l=0;l<16;l++){
      int p = tid + 256*l;                    // 4096 elems: 128 d x 32 r
      int d = p >> 5, r = p & 31;
      Kt[((size_t)(b*DK_ + d))*S_ + s0 + r] = Tmp[r*133 + d];
    }
  }
}

// ---- scores: raw s -> attn (upper tiles & masked entries = 0); column max ----
__global__ __launch_bounds__(256) void scores_kernel(
    const float* __restrict__ Q, const float* __restrict__ Kt,
    float* __restrict__ attn, unsigned* __restrict__ cmax)
{
  const int tj = blockIdx.x, ti = blockIdx.y, b = blockIdx.z;
  const int tid = threadIdx.x;
  const int q0 = ti*64, k0 = tj*64;
  if(tj > ti){                                 // upper triangle: zero-fill tile
    float4 z = {0.f,0.f,0.f,0.f};
    #pragma unroll
    for(int l=0;l<4;l++){
      int p = tid + 256*l;
      int r = p >> 4, c = (p & 15) << 2;
      *reinterpret_cast<float4*>(&attn[((size_t)(b*S_) + q0 + r)*S_ + k0 + c]) = z;
    }
    return;
  }
  __shared__ __align__(16) float Qs[64][132];
  __shared__ __align__(16) float Kst[128][68];
  __shared__ float cred[16][64];
  #pragma unroll
  for(int l=0;l<8;l++){                        // Q tile 64x128
    int p = tid + 256*l;
    int r = p >> 5, c = (p & 31) << 2;
    *reinterpret_cast<float4*>(&Qs[r][c]) =
      *reinterpret_cast<const float4*>(&Q[((size_t)(b*S_ + q0 + r))*DK_ + c]);
  }
  #pragma unroll
  for(int l=0;l<8;l++){                        // K^T tile 128x64
    int p = tid + 256*l;
    int d = p >> 4, c = (p & 15) << 2;
    *reinterpret_cast<float4*>(&Kst[d][c]) =
      *reinterpret_cast<const float4*>(&Kt[((size_t)(b*DK_ + d))*S_ + k0 + c]);
  }
  __syncthreads();
  const int tx = tid & 15, ty = tid >> 4;      // cols 4*tx.., rows 4*ty..
  float acc[4][4] = {};
  #pragma unroll 8
  for(int k=0;k<128;k++){
    float4 kv = *reinterpret_cast<const float4*>(&Kst[k][tx*4]);
    #pragma unroll
    for(int i=0;i<4;i++){
      float qv = Qs[ty*4+i][k];
      acc[i][0]=fmaf(qv,kv.x,acc[i][0]); acc[i][1]=fmaf(qv,kv.y,acc[i][1]);
      acc[i][2]=fmaf(qv,kv.z,acc[i][2]); acc[i][3]=fmaf(qv,kv.w,acc[i][3]);
    }
  }
  float cm[4] = {-INFINITY,-INFINITY,-INFINITY,-INFINITY};
  const bool full = (ti > tj);
  #pragma unroll
  for(int i=0;i<4;i++){
    int q = q0 + ty*4 + i;
    size_t base = ((size_t)(b*S_) + q)*S_ + k0 + tx*4;
    float s[4];
    #pragma unroll
    for(int j=0;j<4;j++) s[j] = acc[i][j]*SCALE;
    float4 v;
    bool v0 = full || (q >= k0 + tx*4 + 0);
    bool v1 = full || (q >= k0 + tx*4 + 1);
    bool v2 = full || (q >= k0 + tx*4 + 2);
    bool v3 = full || (q >= k0 + tx*4 + 3);
    v.x = v0 ? s[0] : 0.f;  v.y = v1 ? s[1] : 0.f;
    v.z = v2 ? s[2] : 0.f;  v.w = v3 ? s[3] : 0.f;
    *reinterpret_cast<float4*>(&attn[base]) = v;
    if(v0) cm[0]=fmaxf(cm[0],s[0]);
    if(v1) cm[1]=fmaxf(cm[1],s[1]);
    if(v2) cm[2]=fmaxf(cm[2],s[2]);
    if(v3) cm[3]=fmaxf(cm[3],s[3]);
  }
  #pragma unroll
  for(int j=0;j<4;j++) cred[ty][tx*4+j] = cm[j];
  __syncthreads();
  if(tid < 64){
    float m = cred[0][tid];
    #pragma unroll
    for(int g=1;g<16;g++) m = fmaxf(m, cred[g][tid]);
    atomicMax(&cmax[b*S_ + k0 + tid], enc_f32(m));
  }
}

// ---- exp + per-column partial sums, float4 in place ----
__global__ __launch_bounds__(256) void expsum_kernel(
    float* __restrict__ attn, const unsigned* __restrict__ cmax,
    float* __restrict__ colpart)
{
  const int cj = blockIdx.x, ti = blockIdx.y, b = blockIdx.z;
  if(ti < 4*cj) return;                        // fully masked block
  __shared__ float part[4][256];
  const int tid = threadIdx.x;
  const int c4 = tid & 63, g = tid >> 6;
  const int q0 = ti*64, k0 = cj*256;
  const int kbase = k0 + c4*4;
  float mc[4];
  #pragma unroll
  for(int j=0;j<4;j++) mc[j] = dec_f32(cmax[b*S_ + kbase + j]);
  float sum[4] = {0.f,0.f,0.f,0.f};
  #pragma unroll 4
  for(int rr=0;rr<16;rr++){
    int q = q0 + g*16 + rr;
    size_t idx = ((size_t)(b*S_) + q)*S_ + kbase;
    float4 sv = *reinterpret_cast<const float4*>(&attn[idx]);
    float4 ev;
    float e0 = __expf(sv.x - mc[0]);
    float e1 = __expf(sv.y - mc[1]);
    float e2 = __expf(sv.z - mc[2]);
    float e3 = __expf(sv.w - mc[3]);
    ev.x = (q >= kbase+0) ? e0 : 0.f;
    ev.y = (q >= kbase+1) ? e1 : 0.f;
    ev.z = (q >= kbase+2) ? e2 : 0.f;
    ev.w = (q >= kbase+3) ? e3 : 0.f;
    *reinterpret_cast<float4*>(&attn[idx]) = ev;
    sum[0]+=ev.x; sum[1]+=ev.y; sum[2]+=ev.z; sum[3]+=ev.w;
  }
  #pragma unroll
  for(int j=0;j<4;j++) part[g][c4*4+j] = sum[j];
  __syncthreads();
  {
    int k = k0 + tid;
    float tot = ((part[0][tid] + part[1][tid]) + part[2][tid]) + part[3][tid];
    colpart[((size_t)(b*S_) + k)*32 + ti] = tot;
  }
}

// ---- column reduce in fixed order -> reciprocal sums ----
__global__ __launch_bounds__(256) void colreduce_kernel(
    const float* __restrict__ colpart, float* __restrict__ rcol)
{
  int i = blockIdx.x*256 + threadIdx.x;  // 0..8191 = b*S + k
  if(i >= B_*S_) return;
  int k = i & (S_-1);
  int t0 = k >> 6;
  float s = 0.f;
  for(int t=t0; t<32; t++) s += colpart[(size_t)i*32 + t];
  rcol[i] = 1.0f / s;
}

// ---- scale V rows by rcol in place: V'[k,:] = V[k,:] * rcol[k] ----
__global__ __launch_bounds__(256) void vscale_kernel(
    float* __restrict__ V, const float* __restrict__ rcol)
{
  int i = blockIdx.x*256 + threadIdx.x;        // f4 index; 262144 total
  float4 v = reinterpret_cast<const float4*>(V)[i];
  float r = rcol[i >> 5];                      // 32 f4 per row; row == b*S + k
  v.x *= r; v.y *= r; v.z *= r; v.w *= r;
  reinterpret_cast<float4*>(V)[i] = v;
}

// ---- PV GEMM partials: LDS-free, barrier-free, split-K; reads raw E and pre-scaled V ----
__global__ __launch_bounds__(256) void pv_kernel(
    const float* __restrict__ attn, const float* __restrict__ Vp,
    float* __restrict__ part, int ns)
{
  const int b = blockIdx.z, tid = threadIdx.x;
  const int sp = blockIdx.y;
  const int tx = tid & 31, ty = tid >> 5;          // cols 4*tx.., rows {ty, ty+8}
  const int t = 127 - (int)blockIdx.x;             // heavy tiles dispatched first
  const int q0 = t*16;
  const int nch = t/4 + 1;
  const int lo = (sp*nch)/ns, hi = ((sp+1)*nch)/ns;
  float acc[2][4] = {{0,0,0,0},{0,0,0,0}};
  const float* Arow0 = attn + ((size_t)(b*S_) + q0 + ty)*S_;
  const float* Arow1 = Arow0 + (size_t)8*S_;
  const float* Vb    = Vp + (size_t)(b*S_)*DK_ + tx*4;
  for(int ch=lo; ch<hi; ++ch){
    const int k0 = ch*64;
    #pragma unroll 4
    for(int kk=0; kk<64; kk+=4){
      float4 e0 = *reinterpret_cast<const float4*>(&Arow0[k0+kk]);
      float4 e1 = *reinterpret_cast<const float4*>(&Arow1[k0+kk]);
      #pragma unroll
      for(int k2=0;k2<4;k2++){
        float4 vv = *reinterpret_cast<const float4*>(&Vb[(size_t)(k0+kk+k2)*DK_]);
        float a0 = f4get(e0,k2), a1 = f4get(e1,k2);
        acc[0][0]=fmaf(a0,vv.x,acc[0][0]); acc[0][1]=fmaf(a0,vv.y,acc[0][1]);
        acc[0][2]=fmaf(a0,vv.z,acc[0][2]); acc[0][3]=fmaf(a0,vv.w,acc[0][3]);
        acc[1][0]=fmaf(a1,vv.x,acc[1][0]); acc[1][1]=fmaf(a1,vv.y,acc[1][1]);
        acc[1][2]=fmaf(a1,vv.z,acc[1][2]); acc[1][3]=fmaf(a1,vv.w,acc[1][3]);
      }
    }
  }
  float* pout = part + (((size_t)(sp*B_ + b))*S_ + q0)*DK_;   // 16 x 128 region
  #pragma unroll
  for(int rr=0;rr<2;rr++){
    float4 o = {acc[rr][0],acc[rr][1],acc[rr][2],acc[rr][3]};
    *reinterpret_cast<float4*>(&pout[(size_t)(ty + rr*8)*DK_ + tx*4]) = o;
  }
}

// ---- sum split-K partials in fixed order ----
__global__ __launch_bounds__(256) void pvreduce_kernel(
    const float* __restrict__ part, float* __restrict__ out, int ns)
{
  const int N4 = (B_*S_*DK_)/4;   // 262144 float4
  int i = blockIdx.x*256 + threadIdx.x;
  if(i >= N4) return;
  const float4* p = reinterpret_cast<const float4*>(part);
  float4 a = p[i];
  for(int s=1; s<ns; ++s){
    float4 q = p[(size_t)s*N4 + i];
    a.x += q.x; a.y += q.y; a.z += q.z; a.w += q.w;
  }
  reinterpret_cast<float4*>(out)[i] = a;
}

// ---- normalize attention in place: attn[q,k] *= rcol[k] (lower-tri blocks only) ----
__global__ __launch_bounds__(256) void attnnorm_kernel(
    float* __restrict__ attn, const float* __restrict__ rcol)
{
  const int cj = blockIdx.x, ti = blockIdx.y, b = blockIdx.z;
  if(ti < 4*cj) return;                        // fully masked block: already zero
  const int tid = threadIdx.x;
  const int c4 = tid & 63, g = tid >> 6;
  const int q0 = ti*64, k0 = cj*256;
  const int kbase = k0 + c4*4;
  float4 r4 = *reinterpret_cast<const float4*>(&rcol[b*S_ + kbase]);
  #pragma unroll 4
  for(int rr=0;rr<16;rr++){
    int q = q0 + g*16 + rr;
    size_t idx = ((size_t)(b*S_) + q)*S_ + kbase;
    float4 e = *reinterpret_cast<const float4*>(&attn[idx]);
    e.x *= r4.x; e.y *= r4.y; e.z *= r4.z; e.w *= r4.w;
    *reinterpret_cast<float4*>(&attn[idx]) = e;
  }
}

extern "C" void kernel_launch(void* const* d_in, const int* in_sizes, int n_in,
                              void* d_out, int out_size, void* d_ws, size_t ws_size,
                              hipStream_t stream)
{
  (void)in_sizes; (void)n_in; (void)out_size;
  const float* X  = (const float*)d_in[0];
  const float* Wq = (const float*)d_in[1];
  const float* Wk = (const float*)d_in[2];
  const float* Wv = (const float*)d_in[3];
  float* out  = (float*)d_out;
  float* attn = out + (size_t)B_*S_*DK_;            // attention output region

  float* ws = (float*)d_ws;
  float* Q       = ws;                               // [4*2048*128]
  float* Kt      = ws + 1048576;                     // [4][128][2048]
  float* V       = ws + 2097152;                     // [4*2048*128]
  unsigned* cmax = (unsigned*)(ws + 3145728);        // [8192]
  float* rcol    = ws + 3145728 + 8192;              // [8192]
  float* colpart = ws + 3145728 + 16384;             // [8192][32]
  const size_t base = 3145728 + 16384 + 262144;      // floats used so far
  float* part    = ws + base;                        // [ns][4][2048][128]

  int ns = 4;
  if(ws_size < (base + (size_t)4*1048576)*sizeof(float)) ns = 2;
  if(ws_size < (base + (size_t)2*1048576)*sizeof(float)) ns = 1;

  init_kernel<<<dim3(32), dim3(256), 0, stream>>>(cmax);
  qkv_kernel<<<dim3(256,3), dim3(256), 0, stream>>>(X, Wq, Wk, Wv, Q, Kt, V);
  scores_kernel<<<dim3(32,32,4), dim3(256), 0, stream>>>(Q, Kt, attn, cmax);
  expsum_kernel<<<dim3(8,32,4), dim3(256), 0, stream>>>(attn, cmax, colpart);
  colreduce_kernel<<<dim3(32), dim3(256), 0, stream>>>(colpart, rcol);
  vscale_kernel<<<dim3(1024), dim3(256), 0, stream>>>(V, rcol);
  pv_kernel<<<dim3(128,ns,4), dim3(256), 0, stream>>>(attn, V, part, ns);
  pvreduce_kernel<<<dim3(1024), dim3(256), 0, stream>>>(part, out, ns);
  attnnorm_kernel<<<dim3(8,32,4), dim3(256), 0, stream>>>(attn, rcol);
}

// Round 7
// 290.575 us; speedup vs baseline: 1.3958x; 1.3958x over previous
//
#include <hip/hip_runtime.h>
#include <math.h>

#define B_ 4
#define S_ 2048
#define DM_ 1024
#define DK_ 128

static constexpr float SCALE = 0.08838834764831845f; // 1/sqrt(128)

__device__ __forceinline__ unsigned enc_f32(float f){
  unsigned u = __float_as_uint(f);
  return (u & 0x80000000u) ? ~u : (u | 0x80000000u);
}
__device__ __forceinline__ float dec_f32(unsigned u){
  unsigned v = (u & 0x80000000u) ? (u & 0x7FFFFFFFu) : ~u;
  return __uint_as_float(v);
}
__device__ __forceinline__ float f4get(const float4& v, int i){
  switch(i){ case 0: return v.x; case 1: return v.y; case 2: return v.z; default: return v.w; }
}

// ---- init: column-max to enc(-inf) ----
__global__ __launch_bounds__(256) void init_kernel(unsigned* __restrict__ cmax){
  int i = blockIdx.x*256 + threadIdx.x;
  if(i < B_*S_) cmax[i] = 0x007FFFFFu; // enc(-INF)
}

// ---- QKV GEMM (32-row tiles, no reg prefetch: proven non-spilling form) ----
__global__ __launch_bounds__(256) void qkv_kernel(
    const float* __restrict__ X, const float* __restrict__ Wq,
    const float* __restrict__ Wk, const float* __restrict__ Wv,
    float* __restrict__ Q, float* __restrict__ Kt, float* __restrict__ V)
{
  __shared__ __align__(16) float smem[32*68 + 64*128];  // Xs[32][68] + Ws[64][128]
  float* Xs = smem;
  float* Ws = smem + 32*68;
  const int tid = threadIdx.x;
  const int which = blockIdx.y;
  const float* Wm = (which==0) ? Wq : ((which==1) ? Wk : Wv);
  const int m0 = blockIdx.x * 32;
  const int tx = tid & 31, ty = tid >> 5;     // cols tx*4.., rows ty*4..
  float acc[4][4] = {};
  for(int k0 = 0; k0 < DM_; k0 += 64){
    __syncthreads();
    #pragma unroll
    for(int l=0;l<2;l++){                     // X tile 32x64
      int p = tid + 256*l;
      int r = p >> 4, c = (p & 15) << 2;
      *reinterpret_cast<float4*>(&Xs[r*68 + c]) =
        *reinterpret_cast<const float4*>(&X[(size_t)(m0+r)*DM_ + k0 + c]);
    }
    #pragma unroll
    for(int l=0;l<8;l++){                     // W tile 64x128 (k-major)
      int p = tid + 256*l;
      int r = p >> 5, c = (p & 31) << 2;
      *reinterpret_cast<float4*>(&Ws[r*128 + c]) =
        *reinterpret_cast<const float4*>(&Wm[(size_t)(k0+r)*DK_ + c]);
    }
    __syncthreads();
    #pragma unroll 4
    for(int kk=0;kk<64;kk+=4){
      float4 xr[4];
      #pragma unroll
      for(int i=0;i<4;i++) xr[i] = *reinterpret_cast<const float4*>(&Xs[(ty*4+i)*68 + kk]);
      #pragma unroll
      for(int k2=0;k2<4;k2++){
        float4 wv = *reinterpret_cast<const float4*>(&Ws[(kk+k2)*128 + tx*4]);
        #pragma unroll
        for(int i=0;i<4;i++){
          float xv = f4get(xr[i], k2);
          acc[i][0] = fmaf(xv, wv.x, acc[i][0]);
          acc[i][1] = fmaf(xv, wv.y, acc[i][1]);
          acc[i][2] = fmaf(xv, wv.z, acc[i][2]);
          acc[i][3] = fmaf(xv, wv.w, acc[i][3]);
        }
      }
    }
  }
  const int b = m0 >> 11;
  if(which != 1){
    float* O = (which==0) ? Q : V;
    #pragma unroll
    for(int i=0;i<4;i++){
      float4 v = {acc[i][0],acc[i][1],acc[i][2],acc[i][3]};
      *reinterpret_cast<float4*>(&O[(size_t)(m0 + ty*4 + i)*DK_ + tx*4]) = v;
    }
  } else {
    __syncthreads();
    float* Tmp = smem;                        // [32][133]
    #pragma unroll
    for(int i=0;i<4;i++)
      #pragma unroll
      for(int j=0;j<4;j++) Tmp[(ty*4+i)*133 + tx*4 + j] = acc[i][j];
    __syncthreads();
    const int s0 = m0 & (S_-1);
    #pragma unroll
    for(int l=0;l<16;l++){
      int p = tid + 256*l;                    // 4096 elems: 128 d x 32 r
      int d = p >> 5, r = p & 31;
      Kt[((size_t)(b*DK_ + d))*S_ + s0 + r] = Tmp[r*133 + d];
    }
  }
}

// ---- scores: raw s -> attn (upper tiles & masked entries = 0); column max ----
__global__ __launch_bounds__(256) void scores_kernel(
    const float* __restrict__ Q, const float* __restrict__ Kt,
    float* __restrict__ attn, unsigned* __restrict__ cmax)
{
  const int tj = blockIdx.x, ti = blockIdx.y, b = blockIdx.z;
  const int tid = threadIdx.x;
  const int q0 = ti*64, k0 = tj*64;
  if(tj > ti){                                 // upper triangle: zero-fill tile
    float4 z = {0.f,0.f,0.f,0.f};
    #pragma unroll
    for(int l=0;l<4;l++){
      int p = tid + 256*l;
      int r = p >> 4, c = (p & 15) << 2;
      *reinterpret_cast<float4*>(&attn[((size_t)(b*S_) + q0 + r)*S_ + k0 + c]) = z;
    }
    return;
  }
  __shared__ __align__(16) float Qs[64][132];
  __shared__ __align__(16) float Kst[128][68];
  __shared__ float cred[16][64];
  #pragma unroll
  for(int l=0;l<8;l++){                        // Q tile 64x128
    int p = tid + 256*l;
    int r = p >> 5, c = (p & 31) << 2;
    *reinterpret_cast<float4*>(&Qs[r][c]) =
      *reinterpret_cast<const float4*>(&Q[((size_t)(b*S_ + q0 + r))*DK_ + c]);
  }
  #pragma unroll
  for(int l=0;l<8;l++){                        // K^T tile 128x64
    int p = tid + 256*l;
    int d = p >> 4, c = (p & 15) << 2;
    *reinterpret_cast<float4*>(&Kst[d][c]) =
      *reinterpret_cast<const float4*>(&Kt[((size_t)(b*DK_ + d))*S_ + k0 + c]);
  }
  __syncthreads();
  const int tx = tid & 15, ty = tid >> 4;      // cols 4*tx.., rows 4*ty..
  float acc[4][4] = {};
  #pragma unroll 8
  for(int k=0;k<128;k++){
    float4 kv = *reinterpret_cast<const float4*>(&Kst[k][tx*4]);
    #pragma unroll
    for(int i=0;i<4;i++){
      float qv = Qs[ty*4+i][k];
      acc[i][0]=fmaf(qv,kv.x,acc[i][0]); acc[i][1]=fmaf(qv,kv.y,acc[i][1]);
      acc[i][2]=fmaf(qv,kv.z,acc[i][2]); acc[i][3]=fmaf(qv,kv.w,acc[i][3]);
    }
  }
  float cm[4] = {-INFINITY,-INFINITY,-INFINITY,-INFINITY};
  const bool full = (ti > tj);
  #pragma unroll
  for(int i=0;i<4;i++){
    int q = q0 + ty*4 + i;
    size_t base = ((size_t)(b*S_) + q)*S_ + k0 + tx*4;
    float s[4];
    #pragma unroll
    for(int j=0;j<4;j++) s[j] = acc[i][j]*SCALE;
    float4 v;
    bool v0 = full || (q >= k0 + tx*4 + 0);
    bool v1 = full || (q >= k0 + tx*4 + 1);
    bool v2 = full || (q >= k0 + tx*4 + 2);
    bool v3 = full || (q >= k0 + tx*4 + 3);
    v.x = v0 ? s[0] : 0.f;  v.y = v1 ? s[1] : 0.f;
    v.z = v2 ? s[2] : 0.f;  v.w = v3 ? s[3] : 0.f;
    *reinterpret_cast<float4*>(&attn[base]) = v;
    if(v0) cm[0]=fmaxf(cm[0],s[0]);
    if(v1) cm[1]=fmaxf(cm[1],s[1]);
    if(v2) cm[2]=fmaxf(cm[2],s[2]);
    if(v3) cm[3]=fmaxf(cm[3],s[3]);
  }
  #pragma unroll
  for(int j=0;j<4;j++) cred[ty][tx*4+j] = cm[j];
  __syncthreads();
  if(tid < 64){
    float m = cred[0][tid];
    #pragma unroll
    for(int g=1;g<16;g++) m = fmaxf(m, cred[g][tid]);
    atomicMax(&cmax[b*S_ + k0 + tid], enc_f32(m));
  }
}

// ---- exp + per-column partial sums, float4 in place ----
__global__ __launch_bounds__(256) void expsum_kernel(
    float* __restrict__ attn, const unsigned* __restrict__ cmax,
    float* __restrict__ colpart)
{
  const int cj = blockIdx.x, ti = blockIdx.y, b = blockIdx.z;
  if(ti < 4*cj) return;                        // fully masked block
  __shared__ float part[4][256];
  const int tid = threadIdx.x;
  const int c4 = tid & 63, g = tid >> 6;
  const int q0 = ti*64, k0 = cj*256;
  const int kbase = k0 + c4*4;
  float mc[4];
  #pragma unroll
  for(int j=0;j<4;j++) mc[j] = dec_f32(cmax[b*S_ + kbase + j]);
  float sum[4] = {0.f,0.f,0.f,0.f};
  #pragma unroll 4
  for(int rr=0;rr<16;rr++){
    int q = q0 + g*16 + rr;
    size_t idx = ((size_t)(b*S_) + q)*S_ + kbase;
    float4 sv = *reinterpret_cast<const float4*>(&attn[idx]);
    float4 ev;
    float e0 = __expf(sv.x - mc[0]);
    float e1 = __expf(sv.y - mc[1]);
    float e2 = __expf(sv.z - mc[2]);
    float e3 = __expf(sv.w - mc[3]);
    ev.x = (q >= kbase+0) ? e0 : 0.f;
    ev.y = (q >= kbase+1) ? e1 : 0.f;
    ev.z = (q >= kbase+2) ? e2 : 0.f;
    ev.w = (q >= kbase+3) ? e3 : 0.f;
    *reinterpret_cast<float4*>(&attn[idx]) = ev;
    sum[0]+=ev.x; sum[1]+=ev.y; sum[2]+=ev.z; sum[3]+=ev.w;
  }
  #pragma unroll
  for(int j=0;j<4;j++) part[g][c4*4+j] = sum[j];
  __syncthreads();
  {
    int k = k0 + tid;
    float tot = ((part[0][tid] + part[1][tid]) + part[2][tid]) + part[3][tid];
    colpart[((size_t)(b*S_) + k)*32 + ti] = tot;
  }
}

// ---- column reduce in fixed order -> reciprocal sums ----
__global__ __launch_bounds__(256) void colreduce_kernel(
    const float* __restrict__ colpart, float* __restrict__ rcol)
{
  int i = blockIdx.x*256 + threadIdx.x;  // 0..8191 = b*S + k
  if(i >= B_*S_) return;
  int k = i & (S_-1);
  int t0 = k >> 6;
  float s = 0.f;
  for(int t=t0; t<32; t++) s += colpart[(size_t)i*32 + t];
  rcol[i] = 1.0f / s;
}

// ---- scale V rows by rcol in place: V'[k,:] = V[k,:] * rcol[k] ----
__global__ __launch_bounds__(256) void vscale_kernel(
    float* __restrict__ V, const float* __restrict__ rcol)
{
  int i = blockIdx.x*256 + threadIdx.x;        // f4 index; 262144 total
  float4 v = reinterpret_cast<const float4*>(V)[i];
  float r = rcol[i >> 5];                      // 32 f4 per row; row == b*S + k
  v.x *= r; v.y *= r; v.z *= r; v.w *= r;
  reinterpret_cast<float4*>(V)[i] = v;
}

// ---- PV GEMM v3: 64x128 tile/block, V chunk in LDS, E broadcast from global ----
__global__ __launch_bounds__(256) void pv_kernel(
    const float* __restrict__ attn, const float* __restrict__ Vp,
    float* __restrict__ part, int ns)
{
  __shared__ __align__(16) float Vs[64][132];
  const int b = blockIdx.z, tid = threadIdx.x;
  const int sp = blockIdx.y;
  const int tx = tid & 31, ty = tid >> 5;          // cols tx*4.., rows ty+8j
  const int t = 31 - (int)blockIdx.x;              // heavy tiles first
  const int q0 = t*64;
  const int nch = t + 1;
  const int lo = (sp*nch)/ns, hi = ((sp+1)*nch)/ns;
  float acc[8][4] = {};
  const float* Arow = attn + ((size_t)(b*S_) + q0 + ty)*S_;   // rows ty+8j via +8j*S_
  for(int ch=lo; ch<hi; ++ch){
    const int k0 = ch*64;
    __syncthreads();
    #pragma unroll
    for(int l=0;l<8;l++){
      int p = tid + 256*l;
      int vr = p >> 5, vc = (p & 31) << 2;
      *reinterpret_cast<float4*>(&Vs[vr][vc]) =
        *reinterpret_cast<const float4*>(&Vp[((size_t)(b*S_) + k0 + vr)*DK_ + vc]);
    }
    __syncthreads();
    #pragma unroll 4
    for(int kk=0; kk<64; kk+=4){
      float4 e[8];
      #pragma unroll
      for(int j=0;j<8;j++)
        e[j] = *reinterpret_cast<const float4*>(&Arow[(size_t)(8*j)*S_ + k0 + kk]);
      #pragma unroll
      for(int k2=0;k2<4;k2++){
        float4 vv = *reinterpret_cast<const float4*>(&Vs[kk+k2][tx*4]);
        #pragma unroll
        for(int j=0;j<8;j++){
          float a = f4get(e[j],k2);
          acc[j][0]=fmaf(a,vv.x,acc[j][0]); acc[j][1]=fmaf(a,vv.y,acc[j][1]);
          acc[j][2]=fmaf(a,vv.z,acc[j][2]); acc[j][3]=fmaf(a,vv.w,acc[j][3]);
        }
      }
    }
  }
  float* pout = part + (((size_t)(sp*B_ + b))*S_ + q0)*DK_;   // 64 x 128 region
  #pragma unroll
  for(int j=0;j<8;j++){
    float4 o = {acc[j][0],acc[j][1],acc[j][2],acc[j][3]};
    *reinterpret_cast<float4*>(&pout[(size_t)(ty + 8*j)*DK_ + tx*4]) = o;
  }
}

// ---- sum split-K partials in fixed order ----
__global__ __launch_bounds__(256) void pvreduce_kernel(
    const float* __restrict__ part, float* __restrict__ out, int ns)
{
  const int N4 = (B_*S_*DK_)/4;   // 262144 float4
  int i = blockIdx.x*256 + threadIdx.x;
  if(i >= N4) return;
  const float4* p = reinterpret_cast<const float4*>(part);
  float4 a = p[i];
  for(int s=1; s<ns; ++s){
    float4 q = p[(size_t)s*N4 + i];
    a.x += q.x; a.y += q.y; a.z += q.z; a.w += q.w;
  }
  reinterpret_cast<float4*>(out)[i] = a;
}

// ---- normalize attention in place: attn[q,k] *= rcol[k] (lower-tri blocks only) ----
__global__ __launch_bounds__(256) void attnnorm_kernel(
    float* __restrict__ attn, const float* __restrict__ rcol)
{
  const int cj = blockIdx.x, ti = blockIdx.y, b = blockIdx.z;
  if(ti < 4*cj) return;                        // fully masked block: already zero
  const int tid = threadIdx.x;
  const int c4 = tid & 63, g = tid >> 6;
  const int q0 = ti*64, k0 = cj*256;
  const int kbase = k0 + c4*4;
  float4 r4 = *reinterpret_cast<const float4*>(&rcol[b*S_ + kbase]);
  #pragma unroll 4
  for(int rr=0;rr<16;rr++){
    int q = q0 + g*16 + rr;
    size_t idx = ((size_t)(b*S_) + q)*S_ + kbase;
    float4 e = *reinterpret_cast<const float4*>(&attn[idx]);
    e.x *= r4.x; e.y *= r4.y; e.z *= r4.z; e.w *= r4.w;
    *reinterpret_cast<float4*>(&attn[idx]) = e;
  }
}

extern "C" void kernel_launch(void* const* d_in, const int* in_sizes, int n_in,
                              void* d_out, int out_size, void* d_ws, size_t ws_size,
                              hipStream_t stream)
{
  (void)in_sizes; (void)n_in; (void)out_size;
  const float* X  = (const float*)d_in[0];
  const float* Wq = (const float*)d_in[1];
  const float* Wk = (const float*)d_in[2];
  const float* Wv = (const float*)d_in[3];
  float* out  = (float*)d_out;
  float* attn = out + (size_t)B_*S_*DK_;            // attention output region

  float* ws = (float*)d_ws;
  float* Q       = ws;                               // [4*2048*128]
  float* Kt      = ws + 1048576;                     // [4][128][2048]
  float* V       = ws + 2097152;                     // [4*2048*128]
  unsigned* cmax = (unsigned*)(ws + 3145728);        // [8192]
  float* rcol    = ws + 3145728 + 8192;              // [8192]
  float* colpart = ws + 3145728 + 16384;             // [8192][32]
  const size_t base = 3145728 + 16384 + 262144;      // floats used so far
  float* part    = ws + base;                        // [ns][4][2048][128]

  int ns = 4;
  if(ws_size < (base + (size_t)4*1048576)*sizeof(float)) ns = 2;
  if(ws_size < (base + (size_t)2*1048576)*sizeof(float)) ns = 1;

  init_kernel<<<dim3(32), dim3(256), 0, stream>>>(cmax);
  qkv_kernel<<<dim3(256,3), dim3(256), 0, stream>>>(X, Wq, Wk, Wv, Q, Kt, V);
  scores_kernel<<<dim3(32,32,4), dim3(256), 0, stream>>>(Q, Kt, attn, cmax);
  expsum_kernel<<<dim3(8,32,4), dim3(256), 0, stream>>>(attn, cmax, colpart);
  colreduce_kernel<<<dim3(32), dim3(256), 0, stream>>>(colpart, rcol);
  vscale_kernel<<<dim3(1024), dim3(256), 0, stream>>>(V, rcol);
  pv_kernel<<<dim3(32,ns,4), dim3(256), 0, stream>>>(attn, V, part, ns);
  pvreduce_kernel<<<dim3(1024), dim3(256), 0, stream>>>(part, out, ns);
  attnnorm_kernel<<<dim3(8,32,4), dim3(256), 0, stream>>>(attn, rcol);
}